// Round 9
// baseline (178.974 us; speedup 1.0000x reference)
//
#include <hip/hip_runtime.h>
#include <stdint.h>

// Problem constants
#define DIM    512
#define HEADS  8
#define DHEAD  64
#define SEQ    2048
#define BATCH  4
#define BH     (BATCH*HEADS)   // 32
#define MROWS  (BATCH*SEQ)     // 8192
#define NQKV   (3*DIM)         // 1536
// SCALE * log2(e): Q pre-scaled so softmax runs in base-2 domain.
#define QSCALE 0.18033688011112042f

typedef __bf16 bf16x8 __attribute__((ext_vector_type(8)));
typedef float  f32x4  __attribute__((ext_vector_type(4)));
typedef float  f32x16 __attribute__((ext_vector_type(16)));

typedef unsigned short u16;

// raw v_exp_f32 (skip ocml range-fixup; |x| << 126 here)
#if __has_builtin(__builtin_amdgcn_exp2f)
#define EXP2(x) __builtin_amdgcn_exp2f(x)
#else
#define EXP2(x) exp2f(x)
#endif

// fp32 -> bf16 (round-to-nearest-even)
__device__ __forceinline__ u16 f2bf(float f) {
    union { float f; uint32_t u; } v; v.f = f;
    uint32_t u = v.u;
    uint32_t r = (u + 0x7FFFu + ((u >> 16) & 1u)) >> 16;
    return (u16)r;
}
__device__ __forceinline__ float bf2f(u16 h) {
    union { uint32_t u; float f; } v; v.u = ((uint32_t)h) << 16;
    return v.f;
}
// pack two fp32 -> dword of 2 bf16, round-half-up via +0x8000 then byte-perm
__device__ __forceinline__ uint32_t pk2bf(float a, float b) {
    union { float f; uint32_t u; } ua, ub; ua.f = a; ub.f = b;
#if __has_builtin(__builtin_amdgcn_perm)
    return __builtin_amdgcn_perm(ub.u + 0x8000u, ua.u + 0x8000u, 0x07060302u);
#else
    return ((ua.u + 0x8000u) >> 16) | ((ub.u + 0x8000u) & 0xFFFF0000u);
#endif
}
// single-instruction pack (T12 recipe): dst.lo = bf16(a), dst.hi = bf16(b)
__device__ __forceinline__ uint32_t cvtpk(float a, float b) {
    uint32_t r;
    asm("v_cvt_pk_bf16_f32 %0, %1, %2" : "=v"(r) : "v"(a), "v"(b));
    return r;
}

// v_permlane32_swap_b32 (gfx950): vdst.hi32 <-> src.lo32.
// Direction HW-verified by R2/R4/R5/R6 pass (p32-only transport).
#define P32SWAP(x, y) asm("v_permlane32_swap_b32 %0, %1" : "+v"(x), "+v"(y))

// async global->LDS copy, 16 B per lane. LDS dest = wave-uniform base + lane*16.
__device__ __forceinline__ void async16(const void* g, u16* l) {
    __builtin_amdgcn_global_load_lds(
        (const __attribute__((address_space(1))) void*)g,
        (__attribute__((address_space(3))) void*)l, 16, 0, 0);
}

// ---------------------------------------------------------------------------
// Fused prep: dtype vote (per-block, deterministic) + pack x (vectorized) +
// LDS-tiled COALESCED weight transposes.
// grid = XBLKS + WQT + WOT blocks.
// ---------------------------------------------------------------------------
#define XBLKS (MROWS * DIM / 4 / 256)            // 4096
#define WQT   ((DIM / 64) * (NQKV / 64))         // 8*24 = 192 tile blocks
#define WOT   ((DIM / 64) * (DIM / 64))          // 8*8  = 64
__global__ void prep(const void* __restrict__ x, const void* __restrict__ wq,
                     const void* __restrict__ wo, u16* __restrict__ xb,
                     u16* __restrict__ wtq, u16* __restrict__ wto,
                     int* __restrict__ flag) {
    __shared__ int cnt;
    __shared__ __align__(16) u16 tile[64][72];   // pad 72: writes 2/bank, rows 16B-aligned
    int tid = threadIdx.x;
    if (tid == 0) cnt = 0;
    __syncthreads();
    {   // dtype vote on first 512 u16 of x (L2-hot, same result in every block)
        u16 v = ((const u16*)x)[tid * 2];
        int e = (v >> 7) & 0xFF;
        atomicAdd(&cnt, (v == 0) || (e >= 100 && e <= 140));
    }
    __syncthreads();
    int isbf = (cnt >= 192);
    int b = blockIdx.x;
    if (b == 0 && tid == 0) *flag = isbf;

    if (b < XBLKS) {
        int i = b * 256 + tid;                   // group of 4 elems
        if (isbf) {
            ((uint2*)xb)[i] = ((const uint2*)x)[i];
        } else {
            float4 v = ((const float4*)x)[i];
            ushort4 o;
            o.x = f2bf(v.x); o.y = f2bf(v.y); o.z = f2bf(v.z); o.w = f2bf(v.w);
            ((ushort4*)xb)[i] = o;
        }
        return;
    }
    // ---- tiled transpose: W[K][N] -> Wt[N][K], 64x64 tile ----
    const void* W; u16* Wt; int N, tb;
    if (b < XBLKS + WQT) { W = wq; Wt = wtq; N = NQKV; tb = b - XBLKS; }
    else                 { W = wo; Wt = wto; N = DIM;  tb = b - XBLKS - WQT; }
    int tn = N / 64;
    int k0 = (tb / tn) * 64, n0 = (tb - (tb / tn) * tn) * 64;

    // load: 16 iters, each wave-row handles one k-row (lanes = consecutive n)
#pragma unroll 4
    for (int it = 0; it < 16; ++it) {
        int idx = it * 256 + tid;                // 4096 elems
        int r = idx >> 6, c = idx & 63;          // r = k-local, c = n-local
        u16 v = isbf ? ((const u16*)W)[(size_t)(k0 + r) * N + n0 + c]
                     : f2bf(((const float*)W)[(size_t)(k0 + r) * N + n0 + c]);
        tile[c][r] = v;                          // transpose in LDS
    }
    __syncthreads();
    // store: thread t -> n-local = t>>2, k-seg = (t&3)*16 (b128 out)
    {
        int n = tid >> 2, ks = (tid & 3) * 16;
        uint4 v0 = *(const uint4*)&tile[n][ks];
        uint4 v1 = *(const uint4*)&tile[n][ks + 8];
        *(uint4*)&Wt[(size_t)(n0 + n) * DIM + k0 + ks] = v0;
        *(uint4*)&Wt[(size_t)(n0 + n) * DIM + k0 + ks + 8] = v1;
    }
}

// ---------------------------------------------------------------------------
// Double-buffered LDS-staged MFMA GEMM core. TMxTN tile, BK=32, 4 waves (2x2).
// ---------------------------------------------------------------------------
template<int KDIM, int TM, int TN>
__device__ __forceinline__ void gemm_lds_db(
        const u16* __restrict__ A, const u16* __restrict__ Bt,
        int m0, int n0, int tid, u16* As, u16* Bs,
        f32x4 (&acc)[TM / 32][TN / 32]) {
    int lane = tid & 63, ln = lane & 15, quad = lane >> 4, w = tid >> 6;
    int wm = (w >> 1) * (TM / 2), wn = (w & 1) * (TN / 2);

    auto stage = [&](int buf, int k0) {
#pragma unroll
        for (int ii = 0; ii < TM / 64; ++ii) {
            int r0 = (ii * 4 + w) * 16;
            int row = r0 + (lane >> 2);
            int seg = (lane & 3) ^ (row & 3);
            async16(A + (size_t)(m0 + row) * KDIM + k0 + seg * 8,
                    As + buf * TM * 32 + r0 * 32);
        }
#pragma unroll
        for (int ii = 0; ii < TN / 64; ++ii) {
            int r0 = (ii * 4 + w) * 16;
            int row = r0 + (lane >> 2);
            int seg = (lane & 3) ^ (row & 3);
            async16(Bt + (size_t)(n0 + row) * KDIM + k0 + seg * 8,
                    Bs + buf * TN * 32 + r0 * 32);
        }
    };

    stage(0, 0);
#pragma unroll 1
    for (int kk = 0; kk < KDIM / 32; ++kk) {
        __syncthreads();
        if (kk + 1 < KDIM / 32) stage((kk + 1) & 1, (kk + 1) * 32);
        const u16* Ac = As + (kk & 1) * TM * 32;
        const u16* Bc = Bs + (kk & 1) * TN * 32;
        bf16x8 a[TM / 32], b[TN / 32];
        int rseg = (quad ^ (ln & 3)) * 8;
#pragma unroll
        for (int i = 0; i < TM / 32; ++i)
            a[i] = *(const bf16x8*)(Ac + (wm + i * 16 + ln) * 32 + rseg);
#pragma unroll
        for (int j = 0; j < TN / 32; ++j)
            b[j] = *(const bf16x8*)(Bc + (wn + j * 16 + ln) * 32 + rseg);
#pragma unroll
        for (int i = 0; i < TM / 32; ++i)
#pragma unroll
            for (int j = 0; j < TN / 32; ++j)
                acc[i][j] = __builtin_amdgcn_mfma_f32_16x16x32_bf16(
                    a[i], b[j], acc[i][j], 0, 0, 0);
    }
}

// ---------------------------------------------------------------------------
// QKV GEMM: 128x128 tile. Q AND V stored transposed [bh][d][n] via in-LDS
// transpose epilogue (coalesced b128 stores, lanes = consecutive n).
// R8 bug fixed: head/dim split now uses the GLOBAL column (n0&511)+col, not
// the tile-local col (that wrote every tile into heads 0-1). K keeps direct
// stores. grid = (64, 12)
// ---------------------------------------------------------------------------
__global__ __launch_bounds__(256, 3) void qkv_gemm(
        const u16* __restrict__ X, const u16* __restrict__ Wt,
        u16* __restrict__ Qt, u16* __restrict__ Kb, u16* __restrict__ Vt) {
    __shared__ __align__(16) u16 SM[16384];        // 32 KB: staging / transpose tile
    u16* As = SM;                                   // 2*128*32
    u16* Bs = SM + 8192;                            // 2*128*32

    int tid  = threadIdx.x;
    int lane = tid & 63, ln = lane & 15, quad = lane >> 4, wid = tid >> 6;
    int m0 = blockIdx.x * 128, n0 = blockIdx.y * 128;
    int wm = (wid >> 1) * 64, wn = (wid & 1) * 64;

    f32x4 acc[4][4];
#pragma unroll
    for (int i = 0; i < 4; ++i)
#pragma unroll
        for (int j = 0; j < 4; ++j) acc[i][j] = 0.f;

    gemm_lds_db<DIM, 128, 128>(X, Wt, m0, n0, tid, As, Bs, acc);

    int which = n0 >> 9;                    // 0=Q 1=K 2=V (uniform per block)
    if (which == 1) {
        // K: [bh][n][d] direct stores (16-lane 32B runs; unchanged)
#pragma unroll
        for (int j = 0; j < 4; ++j) {
            int col = n0 + wn + j * 16 + ln;
            int hd  = col & 511;
            int h   = hd >> 6, d = hd & 63;
#pragma unroll
            for (int i = 0; i < 4; ++i) {
                int rbase = m0 + wm + i * 16 + quad * 4;
                int b = rbase >> 11, n = rbase & 2047;
                int bh = b * HEADS + h;
#pragma unroll
                for (int r = 0; r < 4; ++r)
                    Kb[((size_t)bh * SEQ + n + r) * DHEAD + d] = f2bf(acc[i][j][r]);
            }
        }
        return;
    }

    // ---- Q/V: in-LDS transpose, then coalesced b128 stores ----
    float sc = (which == 0) ? QSCALE : 1.0f;
    u16* dst = (which == 0) ? Qt : Vt;
    int nhd0 = n0 & 511;                     // global column base within Q or V
    __syncthreads();                         // staging LDS dead; reuse as tile

    // phase 1: tile byte layout = col*256 + ((row*2) ^ ((col&7)<<5))
    //   (XOR swizzles 32B groups; keeps 8B/16B alignment intact)
#pragma unroll
    for (int j = 0; j < 4; ++j) {
        int cl = wn + j * 16 + ln;          // col-local 0..127
        int sw = (cl & 7) << 5;
#pragma unroll
        for (int i = 0; i < 4; ++i) {
            int row = wm + i * 16 + quad * 4;   // 4-aligned
            uint2 pv;
            pv.x = pk2bf(acc[i][j][0] * sc, acc[i][j][1] * sc);
            pv.y = pk2bf(acc[i][j][2] * sc, acc[i][j][3] * sc);
            *(uint2*)((char*)SM + (cl << 8) + ((row << 1) ^ sw)) = pv;
        }
    }
    __syncthreads();

    // phase 2: wave w stores cols w*32..w*32+31; per instr: 4 cols x 16 lanes
    // lane ln covers rows ln*8..ln*8+7 (16B) -> global n-consecutive.
    int b = m0 >> 11;                        // uniform: 2048-row batches
    int nbase = m0 & 2047;
#pragma unroll
    for (int it = 0; it < 8; ++it) {
        int col  = wid * 32 + it * 4 + quad;  // tile-local
        int gcol = nhd0 + col;                // global within Q/V [0,512)
        int h = gcol >> 6, d = gcol & 63;
        uint4 v = *(const uint4*)((const char*)SM +
                                  (col << 8) + ((ln << 4) ^ ((col & 7) << 5)));
        *(uint4*)&dst[((size_t)(b * HEADS + h) * DHEAD + d) * SEQ + nbase + ln * 8] = v;
    }
}

// ---------------------------------------------------------------------------
// Flash attention v6 (UNCHANGED from R6, passing at ~52 us): R5 dataflow +
// T4 counted-vmcnt 3-buffer ring + cvt_pk + ones-MFMA denominator.
// ---------------------------------------------------------------------------
__global__ __launch_bounds__(512, 4) void flash_attn(
        const u16* __restrict__ Qt, const u16* __restrict__ Kb,
        const u16* __restrict__ Vt, u16* __restrict__ Ob) {
    // staging: 3 bufs x (4KB K + 4KB V) = 48 KB; combine view aliases
    __shared__ __align__(16) u16 SMEM[24576];      // 48 KB
    __shared__ float Lcomb[4][32];
    u16* Kc0 = SMEM;                                // K bufs: buf*4096
    u16* Vc0 = SMEM + 12288;                        // V bufs: buf*4096
    float* OC = (float*)SMEM;                       // combine view

    int tid  = threadIdx.x;
    int lane = tid & 63, c = lane & 31, hi = lane >> 5, wid = tid >> 6;
    int ws = wid & 1, wq = wid >> 1;               // key-slice, q-tile
    int bh = blockIdx.x;
    int q0 = blockIdx.y * 128 + wq * 32;

    const u16* Qh = Qt + (size_t)bh * SEQ * DHEAD;   // [d][n]
    const u16* Kh = Kb + (size_t)bh * SEQ * DHEAD;   // [n][d]
    const u16* Vh = Vt + (size_t)bh * DHEAD * SEQ;   // [d][n]

    int srow = lane >> 3;                 // row within 8-row slab
    auto stageKV = [&](int buf, int kc) {
        int slab = wid;                   // 0..7: wave stages 1 K-slab + 1 V-slab
        int g = (lane & 7) ^ srow ^ (slab & 3);
        const u16* gk = Kh + (size_t)(kc + slab * 8 + srow) * DHEAD + g * 8;
        async16(gk, Kc0 + buf * 4096 + slab * 8 * 64);
        const u16* gv = Vh + (size_t)(slab * 8 + srow) * SEQ + kc + g * 8;
        async16(gv, Vc0 + buf * 4096 + slab * 8 * 64);
    };

    // Q B-fragments (once per kernel)
    bf16x8 qf[4];
#pragma unroll
    for (int ds = 0; ds < 4; ++ds) {
        union { u16 a[8]; bf16x8 v; } u;
#pragma unroll
        for (int j = 0; j < 8; ++j)
            u.a[j] = Qh[(size_t)(ds * 16 + hi * 8 + j) * SEQ + q0 + c];
        qf[ds] = u.v;
    }

    bf16x8 onesf;
    { union { uint32_t d[4]; bf16x8 v; } u;
      u.d[0] = u.d[1] = u.d[2] = u.d[3] = 0x3F803F80u; onesf = u.v; }

    f32x16 o[2];
    f32x16 lacc;
    lacc = 0.f;
#pragma unroll
    for (int dt = 0; dt < 2; ++dt) o[dt] = 0.f;

    stageKV(0, 0);
    stageKV(1, 64);

    int fl = (c & 7) ^ ((c >> 3) & 3);
    int cur = 0;

#pragma unroll 1
    for (int kc = 0; kc < SEQ; kc += 64) {
        if (kc + 64 < SEQ) asm volatile("s_waitcnt vmcnt(2)" ::: "memory");
        else               asm volatile("s_waitcnt vmcnt(0)" ::: "memory");
        __builtin_amdgcn_s_barrier();
        __builtin_amdgcn_sched_barrier(0);
        if (kc + 128 < SEQ) stageKV((cur + 2) % 3, kc + 128);

        const u16* Kcur = Kc0 + cur * 4096;
        const u16* Vcur = Vc0 + cur * 4096;

        bf16x8 kf[4];
#pragma unroll
        for (int ds = 0; ds < 4; ++ds) {
            int slot = (ds * 2 + hi) ^ fl;
            kf[ds] = *(const bf16x8*)&Kcur[(ws * 32 + c) * 64 + slot * 8];
        }

        f32x16 s;
        s = 0.f;
        __builtin_amdgcn_s_setprio(1);
#pragma unroll
        for (int ds = 0; ds < 4; ++ds)
            s = __builtin_amdgcn_mfma_f32_32x32x16_bf16(
                kf[ds], qf[ds], s, 0, 0, 0);
        __builtin_amdgcn_s_setprio(0);

        float p[16];
#pragma unroll
        for (int r = 0; r < 16; ++r) p[r] = EXP2(s[r]);
        uint32_t X[8];
#pragma unroll
        for (int i = 0; i < 8; ++i) X[i] = cvtpk(p[2 * i], p[2 * i + 1]);
        P32SWAP(X[0], X[2]); P32SWAP(X[1], X[3]);
        P32SWAP(X[4], X[6]); P32SWAP(X[5], X[7]);
        bf16x8 pa[2];
        union { uint32_t d[4]; bf16x8 v; } u0, u1;
        u0.d[0] = X[0]; u0.d[1] = X[1]; u0.d[2] = X[2]; u0.d[3] = X[3];
        u1.d[0] = X[4]; u1.d[1] = X[5]; u1.d[2] = X[6]; u1.d[3] = X[7];
        pa[0] = u0.v; pa[1] = u1.v;

        __builtin_amdgcn_s_setprio(1);
#pragma unroll
        for (int tl = 0; tl < 2; ++tl) {
#pragma unroll
            for (int dt = 0; dt < 2; ++dt) {
                int slot = ((ws * 2 + tl) * 2 + hi) ^ fl;
                bf16x8 vf = *(const bf16x8*)&Vcur[(dt * 32 + c) * 64 + slot * 8];
                o[dt] = __builtin_amdgcn_mfma_f32_32x32x16_bf16(
                    pa[tl], vf, o[dt], 0, 0, 0);
            }
            lacc = __builtin_amdgcn_mfma_f32_32x32x16_bf16(
                pa[tl], onesf, lacc, 0, 0, 0);
        }
        __builtin_amdgcn_s_setprio(0);

        cur = (cur == 2) ? 0 : cur + 1;
    }

    __syncthreads();                       // staging dead; OC view safe

    if (ws == 1) {
#pragma unroll
        for (int dt = 0; dt < 2; ++dt) {
            int base = (((wq * 2 + dt) * 2 + hi) * 32 + c) * 18;
#pragma unroll
            for (int g = 0; g < 4; ++g) {
                f32x4 v;
                v[0] = o[dt][g * 4 + 0]; v[1] = o[dt][g * 4 + 1];
                v[2] = o[dt][g * 4 + 2]; v[3] = o[dt][g * 4 + 3];
                *(f32x4*)&OC[base + g * 4] = v;
            }
        }
        if (c == 0) {
#pragma unroll
            for (int r = 0; r < 16; ++r)
                Lcomb[wq][(r & 3) + 8 * (r >> 2) + 4 * hi] = lacc[r];
        }
    }
    __syncthreads();

    if (ws == 0) {
        int b = bh >> 3, hh = bh & 7;
#pragma unroll
        for (int dt = 0; dt < 2; ++dt) {
            int base = (((wq * 2 + dt) * 2 + hi) * 32 + c) * 18;
#pragma unroll
            for (int g = 0; g < 4; ++g) {
                f32x4 v = *(const f32x4*)&OC[base + g * 4];
                o[dt][g * 4 + 0] += v[0]; o[dt][g * 4 + 1] += v[1];
                o[dt][g * 4 + 2] += v[2]; o[dt][g * 4 + 3] += v[3];
            }
        }
        f32x16 linv;
#pragma unroll
        for (int r = 0; r < 16; ++r)
            linv[r] = 1.0f / (lacc[r] + Lcomb[wq][(r & 3) + 8 * (r >> 2) + 4 * hi]);
#pragma unroll
        for (int dt = 0; dt < 2; ++dt)
#pragma unroll
            for (int r = 0; r < 16; ++r) {
                int ql = (r & 3) + 8 * (r >> 2) + 4 * hi;
                int n  = q0 + ql;
                int d  = dt * 32 + c;
                Ob[((size_t)(b * SEQ + n)) * DIM + hh * DHEAD + d] =
                    f2bf(o[dt][r] * linv[r]);
            }
    }
}

// ---------------------------------------------------------------------------
// Output projection: 64x128 tile, double-buffered, grid (128,4)=512 -> 2/CU.
// ---------------------------------------------------------------------------
__global__ __launch_bounds__(256, 3) void out_gemm(
        const u16* __restrict__ A, const u16* __restrict__ Wt,
        const void* __restrict__ bias, void* __restrict__ out,
        const int* __restrict__ flag) {
    __shared__ __align__(16) u16 As[2 * 64 * 32];
    __shared__ __align__(16) u16 Bs[2 * 128 * 32];

    int tid  = threadIdx.x;
    int lane = tid & 63, ln = lane & 15, quad = lane >> 4, wid = tid >> 6;
    int m0 = blockIdx.x * 64, n0 = blockIdx.y * 128;
    int wm = (wid >> 1) * 32, wn = (wid & 1) * 64;
    int isbf = *flag;

    f32x4 acc[2][4];
#pragma unroll
    for (int i = 0; i < 2; ++i)
#pragma unroll
        for (int j = 0; j < 4; ++j) acc[i][j] = 0.f;

    gemm_lds_db<DIM, 64, 128>(A, Wt, m0, n0, tid, As, Bs, acc);

#pragma unroll
    for (int j = 0; j < 4; ++j) {
        int col = n0 + wn + j * 16 + ln;        // [0,512)
        float bv = isbf ? bf2f(((const u16*)bias)[col])
                        : ((const float*)bias)[col];
#pragma unroll
        for (int i = 0; i < 2; ++i) {
            int rbase = m0 + wm + i * 16 + quad * 4;
#pragma unroll
            for (int r = 0; r < 4; ++r) {
                int row = rbase + r;
                size_t off = (size_t)row * DIM + col;
                float val = acc[i][j][r] + bv;
                if (isbf) ((u16*)out)[off] = f2bf(val);
                else      ((float*)out)[off] = val;
            }
        }
    }
}

// ---------------------------------------------------------------------------
// kernel_launch — 4 launches: prep, qkv_gemm, flash_attn, out_gemm
// ---------------------------------------------------------------------------
extern "C" void kernel_launch(void* const* d_in, const int* in_sizes, int n_in,
                              void* d_out, int out_size, void* d_ws, size_t ws_size,
                              hipStream_t stream) {
    const void* x     = d_in[0];
    const void* w_qkv = d_in[1];
    const void* w_out = d_in[2];
    const void* b_out = d_in[3];

    int* flag   = (int*)d_ws;
    u16* x_bf   = (u16*)((char*)d_ws + 16);                 // 8192*512 (reused as attn)
    u16* wt_qkv = x_bf + (size_t)MROWS * DIM;               // 1536*512
    u16* wt_out = wt_qkv + (size_t)NQKV * DIM;              // 512*512
    u16* Qt     = wt_out + (size_t)DIM * DIM;               // 32*64*2048 [bh][d][n]
    u16* Kb     = Qt + (size_t)BH * SEQ * DHEAD;            // [bh][n][d]
    u16* Vt     = Kb + (size_t)BH * SEQ * DHEAD;            // [bh][d][n]
    u16* attn   = x_bf;                                     // alias: x dead after qkv_gemm

    prep<<<XBLKS + WQT + WOT, 256, 0, stream>>>(
        x, w_qkv, w_out, x_bf, wt_qkv, wt_out, flag);
    qkv_gemm<<<dim3(MROWS / 128, NQKV / 128), 256, 0, stream>>>(x_bf, wt_qkv, Qt, Kb, Vt);
    flash_attn<<<dim3(BH, SEQ / 128), 512, 0, stream>>>(Qt, Kb, Vt, attn);
    out_gemm<<<dim3(MROWS / 64, DIM / 128), 256, 0, stream>>>(attn, wt_out, b_out, d_out, flag);
}

// Round 10
// 177.483 us; speedup vs baseline: 1.0084x; 1.0084x over previous
//
#include <hip/hip_runtime.h>
#include <stdint.h>

// Problem constants
#define DIM    512
#define HEADS  8
#define DHEAD  64
#define SEQ    2048
#define BATCH  4
#define BH     (BATCH*HEADS)   // 32
#define MROWS  (BATCH*SEQ)     // 8192
#define NQKV   (3*DIM)         // 1536
// SCALE * log2(e): Q pre-scaled so softmax runs in base-2 domain.
#define QSCALE 0.18033688011112042f

typedef __bf16 bf16x8 __attribute__((ext_vector_type(8)));
typedef float  f32x4  __attribute__((ext_vector_type(4)));
typedef float  f32x16 __attribute__((ext_vector_type(16)));

typedef unsigned short u16;

// raw v_exp_f32 (skip ocml range-fixup; |x| << 126 here)
#if __has_builtin(__builtin_amdgcn_exp2f)
#define EXP2(x) __builtin_amdgcn_exp2f(x)
#else
#define EXP2(x) exp2f(x)
#endif

// fp32 -> bf16 (round-to-nearest-even)
__device__ __forceinline__ u16 f2bf(float f) {
    union { float f; uint32_t u; } v; v.f = f;
    uint32_t u = v.u;
    uint32_t r = (u + 0x7FFFu + ((u >> 16) & 1u)) >> 16;
    return (u16)r;
}
__device__ __forceinline__ float bf2f(u16 h) {
    union { uint32_t u; float f; } v; v.u = ((uint32_t)h) << 16;
    return v.f;
}
// pack two fp32 -> dword of 2 bf16, round-half-up via +0x8000 then byte-perm
__device__ __forceinline__ uint32_t pk2bf(float a, float b) {
    union { float f; uint32_t u; } ua, ub; ua.f = a; ub.f = b;
#if __has_builtin(__builtin_amdgcn_perm)
    return __builtin_amdgcn_perm(ub.u + 0x8000u, ua.u + 0x8000u, 0x07060302u);
#else
    return ((ua.u + 0x8000u) >> 16) | ((ub.u + 0x8000u) & 0xFFFF0000u);
#endif
}
// single-instruction pack (T12 recipe): dst.lo = bf16(a), dst.hi = bf16(b)
__device__ __forceinline__ uint32_t cvtpk(float a, float b) {
    uint32_t r;
    asm("v_cvt_pk_bf16_f32 %0, %1, %2" : "=v"(r) : "v"(a), "v"(b));
    return r;
}

// v_permlane32_swap_b32 (gfx950): vdst.hi32 <-> src.lo32.
// Direction HW-verified by R2/R4/R5/R6/R9 pass (p32-only transport).
#define P32SWAP(x, y) asm("v_permlane32_swap_b32 %0, %1" : "+v"(x), "+v"(y))

// async global->LDS copy, 16 B per lane. LDS dest = wave-uniform base + lane*16.
__device__ __forceinline__ void async16(const void* g, u16* l) {
    __builtin_amdgcn_global_load_lds(
        (const __attribute__((address_space(1))) void*)g,
        (__attribute__((address_space(3))) void*)l, 16, 0, 0);
}

// ---------------------------------------------------------------------------
// Fused prep: dtype vote (per-block, deterministic) + pack x (vectorized) +
// LDS-tiled COALESCED weight transposes.  (UNCHANGED from R9, passing)
// grid = XBLKS + WQT + WOT blocks.
// ---------------------------------------------------------------------------
#define XBLKS (MROWS * DIM / 4 / 256)            // 4096
#define WQT   ((DIM / 64) * (NQKV / 64))         // 8*24 = 192 tile blocks
#define WOT   ((DIM / 64) * (DIM / 64))          // 8*8  = 64
__global__ void prep(const void* __restrict__ x, const void* __restrict__ wq,
                     const void* __restrict__ wo, u16* __restrict__ xb,
                     u16* __restrict__ wtq, u16* __restrict__ wto,
                     int* __restrict__ flag) {
    __shared__ int cnt;
    __shared__ __align__(16) u16 tile[64][72];   // pad 72: writes 2/bank, rows 16B-aligned
    int tid = threadIdx.x;
    if (tid == 0) cnt = 0;
    __syncthreads();
    {   // dtype vote on first 512 u16 of x (L2-hot, same result in every block)
        u16 v = ((const u16*)x)[tid * 2];
        int e = (v >> 7) & 0xFF;
        atomicAdd(&cnt, (v == 0) || (e >= 100 && e <= 140));
    }
    __syncthreads();
    int isbf = (cnt >= 192);
    int b = blockIdx.x;
    if (b == 0 && tid == 0) *flag = isbf;

    if (b < XBLKS) {
        int i = b * 256 + tid;                   // group of 4 elems
        if (isbf) {
            ((uint2*)xb)[i] = ((const uint2*)x)[i];
        } else {
            float4 v = ((const float4*)x)[i];
            ushort4 o;
            o.x = f2bf(v.x); o.y = f2bf(v.y); o.z = f2bf(v.z); o.w = f2bf(v.w);
            ((ushort4*)xb)[i] = o;
        }
        return;
    }
    // ---- tiled transpose: W[K][N] -> Wt[N][K], 64x64 tile ----
    const void* W; u16* Wt; int N, tb;
    if (b < XBLKS + WQT) { W = wq; Wt = wtq; N = NQKV; tb = b - XBLKS; }
    else                 { W = wo; Wt = wto; N = DIM;  tb = b - XBLKS - WQT; }
    int tn = N / 64;
    int k0 = (tb / tn) * 64, n0 = (tb - (tb / tn) * tn) * 64;

    // load: 16 iters, each wave-row handles one k-row (lanes = consecutive n)
#pragma unroll 4
    for (int it = 0; it < 16; ++it) {
        int idx = it * 256 + tid;                // 4096 elems
        int r = idx >> 6, c = idx & 63;          // r = k-local, c = n-local
        u16 v = isbf ? ((const u16*)W)[(size_t)(k0 + r) * N + n0 + c]
                     : f2bf(((const float*)W)[(size_t)(k0 + r) * N + n0 + c]);
        tile[c][r] = v;                          // transpose in LDS
    }
    __syncthreads();
    // store: thread t -> n-local = t>>2, k-seg = (t&3)*16 (b128 out)
    {
        int n = tid >> 2, ks = (tid & 3) * 16;
        uint4 v0 = *(const uint4*)&tile[n][ks];
        uint4 v1 = *(const uint4*)&tile[n][ks + 8];
        *(uint4*)&Wt[(size_t)(n0 + n) * DIM + k0 + ks] = v0;
        *(uint4*)&Wt[(size_t)(n0 + n) * DIM + k0 + ks + 8] = v1;
    }
}

// ---------------------------------------------------------------------------
// LDS-staged MFMA GEMM core, T4 counted-vmcnt 3-buffer ring (flash-R6
// pattern, proven): per K-step: s_waitcnt vmcnt(LW) -> raw s_barrier ->
// sched_barrier(0) -> stage(k+2) -> ds_read/MFMA. The global_load_lds queue
// never drains in the main loop (the old __syncthreads forced a full
// vmcnt(0) drain every 32-K step = the m97/m233 structural stall).
// Ring safety: buf (k+2)%3 last read at step k-1, sealed by this barrier;
// vmcnt(LW) retires exactly step k's LW loads per wave (step k+1's remain).
// ---------------------------------------------------------------------------
template<int KDIM, int TM, int TN>
__device__ __forceinline__ void gemm_lds_ring(
        const u16* __restrict__ A, const u16* __restrict__ Bt,
        int m0, int n0, int tid, u16* As, u16* Bs,
        f32x4 (&acc)[TM / 32][TN / 32]) {
    constexpr int KN = KDIM / 32;
    constexpr int LW = TM / 64 + TN / 64;   // async16 per wave per stage
    int lane = tid & 63, ln = lane & 15, quad = lane >> 4, w = tid >> 6;
    int wm = (w >> 1) * (TM / 2), wn = (w & 1) * (TN / 2);

    auto stage = [&](int buf, int k0) {
#pragma unroll
        for (int ii = 0; ii < TM / 64; ++ii) {
            int r0 = (ii * 4 + w) * 16;
            int row = r0 + (lane >> 2);
            int seg = (lane & 3) ^ (row & 3);
            async16(A + (size_t)(m0 + row) * KDIM + k0 + seg * 8,
                    As + buf * TM * 32 + r0 * 32);
        }
#pragma unroll
        for (int ii = 0; ii < TN / 64; ++ii) {
            int r0 = (ii * 4 + w) * 16;
            int row = r0 + (lane >> 2);
            int seg = (lane & 3) ^ (row & 3);
            async16(Bt + (size_t)(n0 + row) * KDIM + k0 + seg * 8,
                    Bs + buf * TN * 32 + r0 * 32);
        }
    };

    stage(0, 0);
    stage(1, 32);
#pragma unroll 1
    for (int kk = 0; kk < KN; ++kk) {
        if (kk + 1 < KN) asm volatile("s_waitcnt vmcnt(%0)" :: "i"(LW) : "memory");
        else             asm volatile("s_waitcnt vmcnt(0)" ::: "memory");
        __builtin_amdgcn_s_barrier();
        __builtin_amdgcn_sched_barrier(0);
        if (kk + 2 < KN) stage((kk + 2) % 3, (kk + 2) * 32);

        const u16* Ac = As + (kk % 3) * TM * 32;
        const u16* Bc = Bs + (kk % 3) * TN * 32;
        bf16x8 a[TM / 32], b[TN / 32];
        int rseg = (quad ^ (ln & 3)) * 8;
#pragma unroll
        for (int i = 0; i < TM / 32; ++i)
            a[i] = *(const bf16x8*)(Ac + (wm + i * 16 + ln) * 32 + rseg);
#pragma unroll
        for (int j = 0; j < TN / 32; ++j)
            b[j] = *(const bf16x8*)(Bc + (wn + j * 16 + ln) * 32 + rseg);
#pragma unroll
        for (int i = 0; i < TM / 32; ++i)
#pragma unroll
            for (int j = 0; j < TN / 32; ++j)
                acc[i][j] = __builtin_amdgcn_mfma_f32_16x16x32_bf16(
                    a[i], b[j], acc[i][j], 0, 0, 0);
    }
}

// ---------------------------------------------------------------------------
// QKV GEMM: 128x128 tile, ring-staged (3 bufs = 48 KB, 3 blocks/CU).
// Q/V stored transposed [bh][d][n] via in-LDS transpose epilogue (R9,
// verified). K direct stores. grid = (64, 12)
// ---------------------------------------------------------------------------
__global__ __launch_bounds__(256, 3) void qkv_gemm(
        const u16* __restrict__ X, const u16* __restrict__ Wt,
        u16* __restrict__ Qt, u16* __restrict__ Kb, u16* __restrict__ Vt) {
    __shared__ __align__(16) u16 SM[24576];        // 48 KB: ring / transpose tile
    u16* As = SM;                                   // 3*128*32 = 12288
    u16* Bs = SM + 12288;                           // 3*128*32 = 12288

    int tid  = threadIdx.x;
    int lane = tid & 63, ln = lane & 15, quad = lane >> 4, wid = tid >> 6;
    int m0 = blockIdx.x * 128, n0 = blockIdx.y * 128;
    int wm = (wid >> 1) * 64, wn = (wid & 1) * 64;

    f32x4 acc[4][4];
#pragma unroll
    for (int i = 0; i < 4; ++i)
#pragma unroll
        for (int j = 0; j < 4; ++j) acc[i][j] = 0.f;

    gemm_lds_ring<DIM, 128, 128>(X, Wt, m0, n0, tid, As, Bs, acc);

    int which = n0 >> 9;                    // 0=Q 1=K 2=V (uniform per block)
    if (which == 1) {
        // K: [bh][n][d] direct stores (16-lane 32B runs; unchanged)
#pragma unroll
        for (int j = 0; j < 4; ++j) {
            int col = n0 + wn + j * 16 + ln;
            int hd  = col & 511;
            int h   = hd >> 6, d = hd & 63;
#pragma unroll
            for (int i = 0; i < 4; ++i) {
                int rbase = m0 + wm + i * 16 + quad * 4;
                int b = rbase >> 11, n = rbase & 2047;
                int bh = b * HEADS + h;
#pragma unroll
                for (int r = 0; r < 4; ++r)
                    Kb[((size_t)bh * SEQ + n + r) * DHEAD + d] = f2bf(acc[i][j][r]);
            }
        }
        return;
    }

    // ---- Q/V: in-LDS transpose, then coalesced b128 stores (R9, verified) ----
    float sc = (which == 0) ? QSCALE : 1.0f;
    u16* dst = (which == 0) ? Qt : Vt;
    int nhd0 = n0 & 511;                     // global column base within Q or V
    __syncthreads();                         // staging LDS dead; reuse as tile

    // phase 1: tile byte layout = col*256 + ((row*2) ^ ((col&7)<<5))
#pragma unroll
    for (int j = 0; j < 4; ++j) {
        int cl = wn + j * 16 + ln;          // col-local 0..127
        int sw = (cl & 7) << 5;
#pragma unroll
        for (int i = 0; i < 4; ++i) {
            int row = wm + i * 16 + quad * 4;   // 4-aligned
            uint2 pv;
            pv.x = pk2bf(acc[i][j][0] * sc, acc[i][j][1] * sc);
            pv.y = pk2bf(acc[i][j][2] * sc, acc[i][j][3] * sc);
            *(uint2*)((char*)SM + (cl << 8) + ((row << 1) ^ sw)) = pv;
        }
    }
    __syncthreads();

    // phase 2: wave w stores cols w*32..w*32+31; 4 cols x 16 lanes per instr
    int b = m0 >> 11;                        // uniform: 2048-row batches
    int nbase = m0 & 2047;
#pragma unroll
    for (int it = 0; it < 8; ++it) {
        int col  = wid * 32 + it * 4 + quad;  // tile-local
        int gcol = nhd0 + col;                // global within Q/V [0,512)
        int h = gcol >> 6, d = gcol & 63;
        uint4 v = *(const uint4*)((const char*)SM +
                                  (col << 8) + ((ln << 4) ^ ((col & 7) << 5)));
        *(uint4*)&dst[((size_t)(b * HEADS + h) * DHEAD + d) * SEQ + nbase + ln * 8] = v;
    }
}

// ---------------------------------------------------------------------------
// Flash attention v6 (UNCHANGED from R6/R9, passing at ~52 us): R5 dataflow +
// T4 counted-vmcnt 3-buffer ring + cvt_pk + ones-MFMA denominator.
// ---------------------------------------------------------------------------
__global__ __launch_bounds__(512, 4) void flash_attn(
        const u16* __restrict__ Qt, const u16* __restrict__ Kb,
        const u16* __restrict__ Vt, u16* __restrict__ Ob) {
    // staging: 3 bufs x (4KB K + 4KB V) = 48 KB; combine view aliases
    __shared__ __align__(16) u16 SMEM[24576];      // 48 KB
    __shared__ float Lcomb[4][32];
    u16* Kc0 = SMEM;                                // K bufs: buf*4096
    u16* Vc0 = SMEM + 12288;                        // V bufs: buf*4096
    float* OC = (float*)SMEM;                       // combine view

    int tid  = threadIdx.x;
    int lane = tid & 63, c = lane & 31, hi = lane >> 5, wid = tid >> 6;
    int ws = wid & 1, wq = wid >> 1;               // key-slice, q-tile
    int bh = blockIdx.x;
    int q0 = blockIdx.y * 128 + wq * 32;

    const u16* Qh = Qt + (size_t)bh * SEQ * DHEAD;   // [d][n]
    const u16* Kh = Kb + (size_t)bh * SEQ * DHEAD;   // [n][d]
    const u16* Vh = Vt + (size_t)bh * DHEAD * SEQ;   // [d][n]

    int srow = lane >> 3;                 // row within 8-row slab
    auto stageKV = [&](int buf, int kc) {
        int slab = wid;                   // 0..7: wave stages 1 K-slab + 1 V-slab
        int g = (lane & 7) ^ srow ^ (slab & 3);
        const u16* gk = Kh + (size_t)(kc + slab * 8 + srow) * DHEAD + g * 8;
        async16(gk, Kc0 + buf * 4096 + slab * 8 * 64);
        const u16* gv = Vh + (size_t)(slab * 8 + srow) * SEQ + kc + g * 8;
        async16(gv, Vc0 + buf * 4096 + slab * 8 * 64);
    };

    // Q B-fragments (once per kernel)
    bf16x8 qf[4];
#pragma unroll
    for (int ds = 0; ds < 4; ++ds) {
        union { u16 a[8]; bf16x8 v; } u;
#pragma unroll
        for (int j = 0; j < 8; ++j)
            u.a[j] = Qh[(size_t)(ds * 16 + hi * 8 + j) * SEQ + q0 + c];
        qf[ds] = u.v;
    }

    bf16x8 onesf;
    { union { uint32_t d[4]; bf16x8 v; } u;
      u.d[0] = u.d[1] = u.d[2] = u.d[3] = 0x3F803F80u; onesf = u.v; }

    f32x16 o[2];
    f32x16 lacc;
    lacc = 0.f;
#pragma unroll
    for (int dt = 0; dt < 2; ++dt) o[dt] = 0.f;

    stageKV(0, 0);
    stageKV(1, 64);

    int fl = (c & 7) ^ ((c >> 3) & 3);
    int cur = 0;

#pragma unroll 1
    for (int kc = 0; kc < SEQ; kc += 64) {
        if (kc + 64 < SEQ) asm volatile("s_waitcnt vmcnt(2)" ::: "memory");
        else               asm volatile("s_waitcnt vmcnt(0)" ::: "memory");
        __builtin_amdgcn_s_barrier();
        __builtin_amdgcn_sched_barrier(0);
        if (kc + 128 < SEQ) stageKV((cur + 2) % 3, kc + 128);

        const u16* Kcur = Kc0 + cur * 4096;
        const u16* Vcur = Vc0 + cur * 4096;

        bf16x8 kf[4];
#pragma unroll
        for (int ds = 0; ds < 4; ++ds) {
            int slot = (ds * 2 + hi) ^ fl;
            kf[ds] = *(const bf16x8*)&Kcur[(ws * 32 + c) * 64 + slot * 8];
        }

        f32x16 s;
        s = 0.f;
        __builtin_amdgcn_s_setprio(1);
#pragma unroll
        for (int ds = 0; ds < 4; ++ds)
            s = __builtin_amdgcn_mfma_f32_32x32x16_bf16(
                kf[ds], qf[ds], s, 0, 0, 0);
        __builtin_amdgcn_s_setprio(0);

        float p[16];
#pragma unroll
        for (int r = 0; r < 16; ++r) p[r] = EXP2(s[r]);
        uint32_t X[8];
#pragma unroll
        for (int i = 0; i < 8; ++i) X[i] = cvtpk(p[2 * i], p[2 * i + 1]);
        P32SWAP(X[0], X[2]); P32SWAP(X[1], X[3]);
        P32SWAP(X[4], X[6]); P32SWAP(X[5], X[7]);
        bf16x8 pa[2];
        union { uint32_t d[4]; bf16x8 v; } u0, u1;
        u0.d[0] = X[0]; u0.d[1] = X[1]; u0.d[2] = X[2]; u0.d[3] = X[3];
        u1.d[0] = X[4]; u1.d[1] = X[5]; u1.d[2] = X[6]; u1.d[3] = X[7];
        pa[0] = u0.v; pa[1] = u1.v;

        __builtin_amdgcn_s_setprio(1);
#pragma unroll
        for (int tl = 0; tl < 2; ++tl) {
#pragma unroll
            for (int dt = 0; dt < 2; ++dt) {
                int slot = ((ws * 2 + tl) * 2 + hi) ^ fl;
                bf16x8 vf = *(const bf16x8*)&Vcur[(dt * 32 + c) * 64 + slot * 8];
                o[dt] = __builtin_amdgcn_mfma_f32_32x32x16_bf16(
                    pa[tl], vf, o[dt], 0, 0, 0);
            }
            lacc = __builtin_amdgcn_mfma_f32_32x32x16_bf16(
                pa[tl], onesf, lacc, 0, 0, 0);
        }
        __builtin_amdgcn_s_setprio(0);

        cur = (cur == 2) ? 0 : cur + 1;
    }

    __syncthreads();                       // staging dead; OC view safe

    if (ws == 1) {
#pragma unroll
        for (int dt = 0; dt < 2; ++dt) {
            int base = (((wq * 2 + dt) * 2 + hi) * 32 + c) * 18;
#pragma unroll
            for (int g = 0; g < 4; ++g) {
                f32x4 v;
                v[0] = o[dt][g * 4 + 0]; v[1] = o[dt][g * 4 + 1];
                v[2] = o[dt][g * 4 + 2]; v[3] = o[dt][g * 4 + 3];
                *(f32x4*)&OC[base + g * 4] = v;
            }
        }
        if (c == 0) {
#pragma unroll
            for (int r = 0; r < 16; ++r)
                Lcomb[wq][(r & 3) + 8 * (r >> 2) + 4 * hi] = lacc[r];
        }
    }
    __syncthreads();

    if (ws == 0) {
        int b = bh >> 3, hh = bh & 7;
#pragma unroll
        for (int dt = 0; dt < 2; ++dt) {
            int base = (((wq * 2 + dt) * 2 + hi) * 32 + c) * 18;
#pragma unroll
            for (int g = 0; g < 4; ++g) {
                f32x4 v = *(const f32x4*)&OC[base + g * 4];
                o[dt][g * 4 + 0] += v[0]; o[dt][g * 4 + 1] += v[1];
                o[dt][g * 4 + 2] += v[2]; o[dt][g * 4 + 3] += v[3];
            }
        }
        f32x16 linv;
#pragma unroll
        for (int r = 0; r < 16; ++r)
            linv[r] = 1.0f / (lacc[r] + Lcomb[wq][(r & 3) + 8 * (r >> 2) + 4 * hi]);
#pragma unroll
        for (int dt = 0; dt < 2; ++dt)
#pragma unroll
            for (int r = 0; r < 16; ++r) {
                int ql = (r & 3) + 8 * (r >> 2) + 4 * hi;
                int n  = q0 + ql;
                int d  = dt * 32 + c;
                Ob[((size_t)(b * SEQ + n)) * DIM + hh * DHEAD + d] =
                    f2bf(o[dt][r] * linv[r]);
            }
    }
}

// ---------------------------------------------------------------------------
// Output projection: 64x128 tile, ring-staged (36 KB), grid (128,4)=512.
// ---------------------------------------------------------------------------
__global__ __launch_bounds__(256, 3) void out_gemm(
        const u16* __restrict__ A, const u16* __restrict__ Wt,
        const void* __restrict__ bias, void* __restrict__ out,
        const int* __restrict__ flag) {
    __shared__ __align__(16) u16 As[3 * 64 * 32];
    __shared__ __align__(16) u16 Bs[3 * 128 * 32];

    int tid  = threadIdx.x;
    int lane = tid & 63, ln = lane & 15, quad = lane >> 4, wid = tid >> 6;
    int m0 = blockIdx.x * 64, n0 = blockIdx.y * 128;
    int wm = (wid >> 1) * 32, wn = (wid & 1) * 64;
    int isbf = *flag;

    f32x4 acc[2][4];
#pragma unroll
    for (int i = 0; i < 2; ++i)
#pragma unroll
        for (int j = 0; j < 4; ++j) acc[i][j] = 0.f;

    gemm_lds_ring<DIM, 64, 128>(A, Wt, m0, n0, tid, As, Bs, acc);

#pragma unroll
    for (int j = 0; j < 4; ++j) {
        int col = n0 + wn + j * 16 + ln;        // [0,512)
        float bv = isbf ? bf2f(((const u16*)bias)[col])
                        : ((const float*)bias)[col];
#pragma unroll
        for (int i = 0; i < 2; ++i) {
            int rbase = m0 + wm + i * 16 + quad * 4;
#pragma unroll
            for (int r = 0; r < 4; ++r) {
                int row = rbase + r;
                size_t off = (size_t)row * DIM + col;
                float val = acc[i][j][r] + bv;
                if (isbf) ((u16*)out)[off] = f2bf(val);
                else      ((float*)out)[off] = val;
            }
        }
    }
}

// ---------------------------------------------------------------------------
// kernel_launch — 4 launches: prep, qkv_gemm, flash_attn, out_gemm
// ---------------------------------------------------------------------------
extern "C" void kernel_launch(void* const* d_in, const int* in_sizes, int n_in,
                              void* d_out, int out_size, void* d_ws, size_t ws_size,
                              hipStream_t stream) {
    const void* x     = d_in[0];
    const void* w_qkv = d_in[1];
    const void* w_out = d_in[2];
    const void* b_out = d_in[3];

    int* flag   = (int*)d_ws;
    u16* x_bf   = (u16*)((char*)d_ws + 16);                 // 8192*512 (reused as attn)
    u16* wt_qkv = x_bf + (size_t)MROWS * DIM;               // 1536*512
    u16* wt_out = wt_qkv + (size_t)NQKV * DIM;              // 512*512
    u16* Qt     = wt_out + (size_t)DIM * DIM;               // 32*64*2048 [bh][d][n]
    u16* Kb     = Qt + (size_t)BH * SEQ * DHEAD;            // [bh][n][d]
    u16* Vt     = Kb + (size_t)BH * SEQ * DHEAD;            // [bh][d][n]
    u16* attn   = x_bf;                                     // alias: x dead after qkv_gemm

    prep<<<XBLKS + WQT + WOT, 256, 0, stream>>>(
        x, w_qkv, w_out, x_bf, wt_qkv, wt_out, flag);
    qkv_gemm<<<dim3(MROWS / 128, NQKV / 128), 256, 0, stream>>>(x_bf, wt_qkv, Qt, Kb, Vt);
    flash_attn<<<dim3(BH, SEQ / 128), 512, 0, stream>>>(Qt, Kb, Vt, attn);
    out_gemm<<<dim3(MROWS / 64, DIM / 128), 256, 0, stream>>>(attn, wt_out, b_out, d_out, flag);
}

// Round 11
// 170.946 us; speedup vs baseline: 1.0470x; 1.0382x over previous
//
#include <hip/hip_runtime.h>
#include <stdint.h>

// Problem constants
#define DIM    512
#define HEADS  8
#define DHEAD  64
#define SEQ    2048
#define BATCH  4
#define BH     (BATCH*HEADS)   // 32
#define MROWS  (BATCH*SEQ)     // 8192
#define NQKV   (3*DIM)         // 1536
// SCALE * log2(e): Q pre-scaled so softmax runs in base-2 domain.
#define QSCALE 0.18033688011112042f

typedef __bf16 bf16x8 __attribute__((ext_vector_type(8)));
typedef float  f32x4  __attribute__((ext_vector_type(4)));
typedef float  f32x16 __attribute__((ext_vector_type(16)));

typedef unsigned short u16;

// raw v_exp_f32 (skip ocml range-fixup; |x| << 126 here)
#if __has_builtin(__builtin_amdgcn_exp2f)
#define EXP2(x) __builtin_amdgcn_exp2f(x)
#else
#define EXP2(x) exp2f(x)
#endif

// fp32 -> bf16 (round-to-nearest-even)
__device__ __forceinline__ u16 f2bf(float f) {
    union { float f; uint32_t u; } v; v.f = f;
    uint32_t u = v.u;
    uint32_t r = (u + 0x7FFFu + ((u >> 16) & 1u)) >> 16;
    return (u16)r;
}
__device__ __forceinline__ float bf2f(u16 h) {
    union { uint32_t u; float f; } v; v.u = ((uint32_t)h) << 16;
    return v.f;
}
// pack two fp32 -> dword of 2 bf16, round-half-up via +0x8000 then byte-perm
__device__ __forceinline__ uint32_t pk2bf(float a, float b) {
    union { float f; uint32_t u; } ua, ub; ua.f = a; ub.f = b;
#if __has_builtin(__builtin_amdgcn_perm)
    return __builtin_amdgcn_perm(ub.u + 0x8000u, ua.u + 0x8000u, 0x07060302u);
#else
    return ((ua.u + 0x8000u) >> 16) | ((ub.u + 0x8000u) & 0xFFFF0000u);
#endif
}
// pack two fp32 -> dword of 2 bf16 with f2bf (RNE) bits — matches the old
// prep x-conversion exactly.
__device__ __forceinline__ uint32_t pk2bf_rne(float a, float b) {
    return (uint32_t)f2bf(a) | ((uint32_t)f2bf(b) << 16);
}
// single-instruction pack (T12 recipe): dst.lo = bf16(a), dst.hi = bf16(b)
__device__ __forceinline__ uint32_t cvtpk(float a, float b) {
    uint32_t r;
    asm("v_cvt_pk_bf16_f32 %0, %1, %2" : "=v"(r) : "v"(a), "v"(b));
    return r;
}

// v_permlane32_swap_b32 (gfx950): vdst.hi32 <-> src.lo32.
// Direction HW-verified by R2/R4/R5/R6/R9/R10 pass (p32-only transport).
#define P32SWAP(x, y) asm("v_permlane32_swap_b32 %0, %1" : "+v"(x), "+v"(y))

// async global->LDS copy, 16 B per lane. LDS dest = wave-uniform base + lane*16.
__device__ __forceinline__ void async16(const void* g, u16* l) {
    __builtin_amdgcn_global_load_lds(
        (const __attribute__((address_space(1))) void*)g,
        (__attribute__((address_space(3))) void*)l, 16, 0, 0);
}

// ---------------------------------------------------------------------------
// prep v2: dtype vote + weight transposes ONLY (x-conversion fused into
// qkv_gemm's A-staging — the old 4096-block x-pass and its 25 MB of
// write+re-read traffic are gone). grid = WQT + WOT = 256 blocks.
// ---------------------------------------------------------------------------
#define WQT   ((DIM / 64) * (NQKV / 64))         // 8*24 = 192 tile blocks
#define WOT   ((DIM / 64) * (DIM / 64))          // 8*8  = 64
__global__ void prep(const void* __restrict__ x, const void* __restrict__ wq,
                     const void* __restrict__ wo,
                     u16* __restrict__ wtq, u16* __restrict__ wto,
                     int* __restrict__ flag) {
    __shared__ int cnt;
    __shared__ __align__(16) u16 tile[64][72];   // pad 72: writes 2/bank, rows 16B-aligned
    int tid = threadIdx.x;
    if (tid == 0) cnt = 0;
    __syncthreads();
    {   // dtype vote on first 512 u16 of x (L2-hot, same result in every block)
        u16 v = ((const u16*)x)[tid * 2];
        int e = (v >> 7) & 0xFF;
        atomicAdd(&cnt, (v == 0) || (e >= 100 && e <= 140));
    }
    __syncthreads();
    int isbf = (cnt >= 192);
    int b = blockIdx.x;
    if (b == 0 && tid == 0) *flag = isbf;

    // ---- tiled transpose: W[K][N] -> Wt[N][K], 64x64 tile ----
    const void* W; u16* Wt; int N, tb;
    if (b < WQT) { W = wq; Wt = wtq; N = NQKV; tb = b; }
    else         { W = wo; Wt = wto; N = DIM;  tb = b - WQT; }
    int tn = N / 64;
    int k0 = (tb / tn) * 64, n0 = (tb - (tb / tn) * tn) * 64;

    // load: 16 iters, each wave-row handles one k-row (lanes = consecutive n)
#pragma unroll 4
    for (int it = 0; it < 16; ++it) {
        int idx = it * 256 + tid;                // 4096 elems
        int r = idx >> 6, c = idx & 63;          // r = k-local, c = n-local
        u16 v = isbf ? ((const u16*)W)[(size_t)(k0 + r) * N + n0 + c]
                     : f2bf(((const float*)W)[(size_t)(k0 + r) * N + n0 + c]);
        tile[c][r] = v;                          // transpose in LDS
    }
    __syncthreads();
    // store: thread t -> n-local = t>>2, k-seg = (t&3)*16 (b128 out)
    {
        int n = tid >> 2, ks = (tid & 3) * 16;
        uint4 v0 = *(const uint4*)&tile[n][ks];
        uint4 v1 = *(const uint4*)&tile[n][ks + 8];
        *(uint4*)&Wt[(size_t)(n0 + n) * DIM + k0 + ks] = v0;
        *(uint4*)&Wt[(size_t)(n0 + n) * DIM + k0 + ks + 8] = v1;
    }
}

// ---------------------------------------------------------------------------
// LDS-staged MFMA GEMM core, 2-buf __syncthreads double-buffer (R4-proven).
// Used by out_gemm (A already bf16).
// ---------------------------------------------------------------------------
template<int KDIM, int TM, int TN>
__device__ __forceinline__ void gemm_lds_db(
        const u16* __restrict__ A, const u16* __restrict__ Bt,
        int m0, int n0, int tid, u16* As, u16* Bs,
        f32x4 (&acc)[TM / 32][TN / 32]) {
    int lane = tid & 63, ln = lane & 15, quad = lane >> 4, w = tid >> 6;
    int wm = (w >> 1) * (TM / 2), wn = (w & 1) * (TN / 2);

    auto stage = [&](int buf, int k0) {
#pragma unroll
        for (int ii = 0; ii < TM / 64; ++ii) {
            int r0 = (ii * 4 + w) * 16;
            int row = r0 + (lane >> 2);
            int seg = (lane & 3) ^ (row & 3);
            async16(A + (size_t)(m0 + row) * KDIM + k0 + seg * 8,
                    As + buf * TM * 32 + r0 * 32);
        }
#pragma unroll
        for (int ii = 0; ii < TN / 64; ++ii) {
            int r0 = (ii * 4 + w) * 16;
            int row = r0 + (lane >> 2);
            int seg = (lane & 3) ^ (row & 3);
            async16(Bt + (size_t)(n0 + row) * KDIM + k0 + seg * 8,
                    Bs + buf * TN * 32 + r0 * 32);
        }
    };

    stage(0, 0);
#pragma unroll 1
    for (int kk = 0; kk < KDIM / 32; ++kk) {
        __syncthreads();
        if (kk + 1 < KDIM / 32) stage((kk + 1) & 1, (kk + 1) * 32);
        const u16* Ac = As + (kk & 1) * TM * 32;
        const u16* Bc = Bs + (kk & 1) * TN * 32;
        bf16x8 a[TM / 32], b[TN / 32];
        int rseg = (quad ^ (ln & 3)) * 8;
#pragma unroll
        for (int i = 0; i < TM / 32; ++i)
            a[i] = *(const bf16x8*)(Ac + (wm + i * 16 + ln) * 32 + rseg);
#pragma unroll
        for (int j = 0; j < TN / 32; ++j)
            b[j] = *(const bf16x8*)(Bc + (wn + j * 16 + ln) * 32 + rseg);
#pragma unroll
        for (int i = 0; i < TM / 32; ++i)
#pragma unroll
            for (int j = 0; j < TN / 32; ++j)
                acc[i][j] = __builtin_amdgcn_mfma_f32_16x16x32_bf16(
                    a[i], b[j], acc[i][j], 0, 0, 0);
    }
}

// ---------------------------------------------------------------------------
// QKV GEMM with FUSED x ingestion: A-staging branches per dtype —
//  * bf16 x: async16 straight from x (byte-identical LDS image to the old
//    x_bf path, which was a verbatim copy).
//  * fp32 x: reg-load 2xfloat4, convert with f2bf (same bits as old prep),
//    ds_write_b128 to the SAME LDS address async16 would use
//    (base + lane*16B). Fragment reads/MFMA/epilogue untouched.
// 2-buf __syncthreads structure (compiler manages lgkm/vm waits for the
// mixed ds_write/global_load_lds staging). Q/V in-LDS transpose epilogue
// (R9/R10, verified). grid = (64, 12)
// ---------------------------------------------------------------------------
__global__ __launch_bounds__(256, 3) void qkv_gemm(
        const void* __restrict__ x, const u16* __restrict__ Wt,
        u16* __restrict__ Qt, u16* __restrict__ Kb, u16* __restrict__ Vt,
        const int* __restrict__ flag) {
    __shared__ __align__(16) u16 SM[16384];        // 32 KB: staging / transpose tile
    u16* As = SM;                                   // 2*128*32 = 8192
    u16* Bs = SM + 8192;                            // 2*128*32 = 8192

    int tid  = threadIdx.x;
    int lane = tid & 63, ln = lane & 15, quad = lane >> 4, wid = tid >> 6;
    int m0 = blockIdx.x * 128, n0 = blockIdx.y * 128;
    int wm = (wid >> 1) * 64, wn = (wid & 1) * 64;
    int isbf = *flag;

    auto stageA = [&](int buf, int k0) {
#pragma unroll
        for (int ii = 0; ii < 2; ++ii) {
            int r0 = (ii * 4 + wid) * 16;
            int row = r0 + (lane >> 2);
            int g = (lane & 3) ^ (row & 3);
            if (isbf) {
                async16((const u16*)x + (size_t)(m0 + row) * DIM + k0 + g * 8,
                        As + buf * 4096 + r0 * 32);
            } else {
                const float* src = (const float*)x + (size_t)(m0 + row) * DIM + k0 + g * 8;
                float4 v0 = *(const float4*)src;
                float4 v1 = *(const float4*)(src + 4);
                uint4 d;
                d.x = pk2bf_rne(v0.x, v0.y);
                d.y = pk2bf_rne(v0.z, v0.w);
                d.z = pk2bf_rne(v1.x, v1.y);
                d.w = pk2bf_rne(v1.z, v1.w);
                // same bytes async16 would write: base + lane*16B
                *(uint4*)(As + buf * 4096 + r0 * 32 + (lane >> 2) * 32 + (lane & 3) * 8) = d;
            }
        }
    };
    auto stageB = [&](int buf, int k0) {
#pragma unroll
        for (int ii = 0; ii < 2; ++ii) {
            int r0 = (ii * 4 + wid) * 16;
            int row = r0 + (lane >> 2);
            int g = (lane & 3) ^ (row & 3);
            async16(Wt + (size_t)(n0 + row) * DIM + k0 + g * 8,
                    Bs + buf * 4096 + r0 * 32);
        }
    };

    f32x4 acc[4][4];
#pragma unroll
    for (int i = 0; i < 4; ++i)
#pragma unroll
        for (int j = 0; j < 4; ++j) acc[i][j] = 0.f;

    stageA(0, 0); stageB(0, 0);
#pragma unroll 1
    for (int kk = 0; kk < 16; ++kk) {
        __syncthreads();
        if (kk + 1 < 16) { stageA((kk + 1) & 1, (kk + 1) * 32);
                           stageB((kk + 1) & 1, (kk + 1) * 32); }
        const u16* Ac = As + (kk & 1) * 4096;
        const u16* Bc = Bs + (kk & 1) * 4096;
        bf16x8 a[4], b[4];
        int rseg = (quad ^ (ln & 3)) * 8;
#pragma unroll
        for (int i = 0; i < 4; ++i)
            a[i] = *(const bf16x8*)(Ac + (wm + i * 16 + ln) * 32 + rseg);
#pragma unroll
        for (int j = 0; j < 4; ++j)
            b[j] = *(const bf16x8*)(Bc + (wn + j * 16 + ln) * 32 + rseg);
#pragma unroll
        for (int i = 0; i < 4; ++i)
#pragma unroll
            for (int j = 0; j < 4; ++j)
                acc[i][j] = __builtin_amdgcn_mfma_f32_16x16x32_bf16(
                    a[i], b[j], acc[i][j], 0, 0, 0);
    }

    int which = n0 >> 9;                    // 0=Q 1=K 2=V (uniform per block)
    if (which == 1) {
        // K: [bh][n][d] direct stores (16-lane 32B runs; unchanged)
#pragma unroll
        for (int j = 0; j < 4; ++j) {
            int col = n0 + wn + j * 16 + ln;
            int hd  = col & 511;
            int h   = hd >> 6, d = hd & 63;
#pragma unroll
            for (int i = 0; i < 4; ++i) {
                int rbase = m0 + wm + i * 16 + quad * 4;
                int b2 = rbase >> 11, n = rbase & 2047;
                int bh = b2 * HEADS + h;
#pragma unroll
                for (int r = 0; r < 4; ++r)
                    Kb[((size_t)bh * SEQ + n + r) * DHEAD + d] = f2bf(acc[i][j][r]);
            }
        }
        return;
    }

    // ---- Q/V: in-LDS transpose, then coalesced b128 stores (R9/R10) ----
    float sc = (which == 0) ? QSCALE : 1.0f;
    u16* dst = (which == 0) ? Qt : Vt;
    int nhd0 = n0 & 511;                     // global column base within Q or V
    __syncthreads();                         // staging LDS dead; reuse as tile

    // phase 1: tile byte layout = col*256 + ((row*2) ^ ((col&7)<<5))
#pragma unroll
    for (int j = 0; j < 4; ++j) {
        int cl = wn + j * 16 + ln;          // col-local 0..127
        int sw = (cl & 7) << 5;
#pragma unroll
        for (int i = 0; i < 4; ++i) {
            int row = wm + i * 16 + quad * 4;   // 4-aligned
            uint2 pv;
            pv.x = pk2bf(acc[i][j][0] * sc, acc[i][j][1] * sc);
            pv.y = pk2bf(acc[i][j][2] * sc, acc[i][j][3] * sc);
            *(uint2*)((char*)SM + (cl << 8) + ((row << 1) ^ sw)) = pv;
        }
    }
    __syncthreads();

    // phase 2: wave w stores cols w*32..w*32+31; 4 cols x 16 lanes per instr
    int b2 = m0 >> 11;                       // uniform: 2048-row batches
    int nbase = m0 & 2047;
#pragma unroll
    for (int it = 0; it < 8; ++it) {
        int col  = wid * 32 + it * 4 + quad;  // tile-local
        int gcol = nhd0 + col;                // global within Q/V [0,512)
        int h = gcol >> 6, d = gcol & 63;
        uint4 v = *(const uint4*)((const char*)SM +
                                  (col << 8) + ((ln << 4) ^ ((col & 7) << 5)));
        *(uint4*)&dst[((size_t)(b2 * HEADS + h) * DHEAD + d) * SEQ + nbase + ln * 8] = v;
    }
}

// ---------------------------------------------------------------------------
// Flash attention v6 (UNCHANGED from R6/R9/R10, passing at ~52 us).
// ---------------------------------------------------------------------------
__global__ __launch_bounds__(512, 4) void flash_attn(
        const u16* __restrict__ Qt, const u16* __restrict__ Kb,
        const u16* __restrict__ Vt, u16* __restrict__ Ob) {
    // staging: 3 bufs x (4KB K + 4KB V) = 48 KB; combine view aliases
    __shared__ __align__(16) u16 SMEM[24576];      // 48 KB
    __shared__ float Lcomb[4][32];
    u16* Kc0 = SMEM;                                // K bufs: buf*4096
    u16* Vc0 = SMEM + 12288;                        // V bufs: buf*4096
    float* OC = (float*)SMEM;                       // combine view

    int tid  = threadIdx.x;
    int lane = tid & 63, c = lane & 31, hi = lane >> 5, wid = tid >> 6;
    int ws = wid & 1, wq = wid >> 1;               // key-slice, q-tile
    int bh = blockIdx.x;
    int q0 = blockIdx.y * 128 + wq * 32;

    const u16* Qh = Qt + (size_t)bh * SEQ * DHEAD;   // [d][n]
    const u16* Kh = Kb + (size_t)bh * SEQ * DHEAD;   // [n][d]
    const u16* Vh = Vt + (size_t)bh * DHEAD * SEQ;   // [d][n]

    int srow = lane >> 3;                 // row within 8-row slab
    auto stageKV = [&](int buf, int kc) {
        int slab = wid;                   // 0..7: wave stages 1 K-slab + 1 V-slab
        int g = (lane & 7) ^ srow ^ (slab & 3);
        const u16* gk = Kh + (size_t)(kc + slab * 8 + srow) * DHEAD + g * 8;
        async16(gk, Kc0 + buf * 4096 + slab * 8 * 64);
        const u16* gv = Vh + (size_t)(slab * 8 + srow) * SEQ + kc + g * 8;
        async16(gv, Vc0 + buf * 4096 + slab * 8 * 64);
    };

    // Q B-fragments (once per kernel)
    bf16x8 qf[4];
#pragma unroll
    for (int ds = 0; ds < 4; ++ds) {
        union { u16 a[8]; bf16x8 v; } u;
#pragma unroll
        for (int j = 0; j < 8; ++j)
            u.a[j] = Qh[(size_t)(ds * 16 + hi * 8 + j) * SEQ + q0 + c];
        qf[ds] = u.v;
    }

    bf16x8 onesf;
    { union { uint32_t d[4]; bf16x8 v; } u;
      u.d[0] = u.d[1] = u.d[2] = u.d[3] = 0x3F803F80u; onesf = u.v; }

    f32x16 o[2];
    f32x16 lacc;
    lacc = 0.f;
#pragma unroll
    for (int dt = 0; dt < 2; ++dt) o[dt] = 0.f;

    stageKV(0, 0);
    stageKV(1, 64);

    int fl = (c & 7) ^ ((c >> 3) & 3);
    int cur = 0;

#pragma unroll 1
    for (int kc = 0; kc < SEQ; kc += 64) {
        if (kc + 64 < SEQ) asm volatile("s_waitcnt vmcnt(2)" ::: "memory");
        else               asm volatile("s_waitcnt vmcnt(0)" ::: "memory");
        __builtin_amdgcn_s_barrier();
        __builtin_amdgcn_sched_barrier(0);
        if (kc + 128 < SEQ) stageKV((cur + 2) % 3, kc + 128);

        const u16* Kcur = Kc0 + cur * 4096;
        const u16* Vcur = Vc0 + cur * 4096;

        bf16x8 kf[4];
#pragma unroll
        for (int ds = 0; ds < 4; ++ds) {
            int slot = (ds * 2 + hi) ^ fl;
            kf[ds] = *(const bf16x8*)&Kcur[(ws * 32 + c) * 64 + slot * 8];
        }

        f32x16 s;
        s = 0.f;
        __builtin_amdgcn_s_setprio(1);
#pragma unroll
        for (int ds = 0; ds < 4; ++ds)
            s = __builtin_amdgcn_mfma_f32_32x32x16_bf16(
                kf[ds], qf[ds], s, 0, 0, 0);
        __builtin_amdgcn_s_setprio(0);

        float p[16];
#pragma unroll
        for (int r = 0; r < 16; ++r) p[r] = EXP2(s[r]);
        uint32_t X[8];
#pragma unroll
        for (int i = 0; i < 8; ++i) X[i] = cvtpk(p[2 * i], p[2 * i + 1]);
        P32SWAP(X[0], X[2]); P32SWAP(X[1], X[3]);
        P32SWAP(X[4], X[6]); P32SWAP(X[5], X[7]);
        bf16x8 pa[2];
        union { uint32_t d[4]; bf16x8 v; } u0, u1;
        u0.d[0] = X[0]; u0.d[1] = X[1]; u0.d[2] = X[2]; u0.d[3] = X[3];
        u1.d[0] = X[4]; u1.d[1] = X[5]; u1.d[2] = X[6]; u1.d[3] = X[7];
        pa[0] = u0.v; pa[1] = u1.v;

        __builtin_amdgcn_s_setprio(1);
#pragma unroll
        for (int tl = 0; tl < 2; ++tl) {
#pragma unroll
            for (int dt = 0; dt < 2; ++dt) {
                int slot = ((ws * 2 + tl) * 2 + hi) ^ fl;
                bf16x8 vf = *(const bf16x8*)&Vcur[(dt * 32 + c) * 64 + slot * 8];
                o[dt] = __builtin_amdgcn_mfma_f32_32x32x16_bf16(
                    pa[tl], vf, o[dt], 0, 0, 0);
            }
            lacc = __builtin_amdgcn_mfma_f32_32x32x16_bf16(
                pa[tl], onesf, lacc, 0, 0, 0);
        }
        __builtin_amdgcn_s_setprio(0);

        cur = (cur == 2) ? 0 : cur + 1;
    }

    __syncthreads();                       // staging dead; OC view safe

    if (ws == 1) {
#pragma unroll
        for (int dt = 0; dt < 2; ++dt) {
            int base = (((wq * 2 + dt) * 2 + hi) * 32 + c) * 18;
#pragma unroll
            for (int g = 0; g < 4; ++g) {
                f32x4 v;
                v[0] = o[dt][g * 4 + 0]; v[1] = o[dt][g * 4 + 1];
                v[2] = o[dt][g * 4 + 2]; v[3] = o[dt][g * 4 + 3];
                *(f32x4*)&OC[base + g * 4] = v;
            }
        }
        if (c == 0) {
#pragma unroll
            for (int r = 0; r < 16; ++r)
                Lcomb[wq][(r & 3) + 8 * (r >> 2) + 4 * hi] = lacc[r];
        }
    }
    __syncthreads();

    if (ws == 0) {
        int b = bh >> 3, hh = bh & 7;
#pragma unroll
        for (int dt = 0; dt < 2; ++dt) {
            int base = (((wq * 2 + dt) * 2 + hi) * 32 + c) * 18;
#pragma unroll
            for (int g = 0; g < 4; ++g) {
                f32x4 v = *(const f32x4*)&OC[base + g * 4];
                o[dt][g * 4 + 0] += v[0]; o[dt][g * 4 + 1] += v[1];
                o[dt][g * 4 + 2] += v[2]; o[dt][g * 4 + 3] += v[3];
            }
        }
        f32x16 linv;
#pragma unroll
        for (int r = 0; r < 16; ++r)
            linv[r] = 1.0f / (lacc[r] + Lcomb[wq][(r & 3) + 8 * (r >> 2) + 4 * hi]);
#pragma unroll
        for (int dt = 0; dt < 2; ++dt)
#pragma unroll
            for (int r = 0; r < 16; ++r) {
                int ql = (r & 3) + 8 * (r >> 2) + 4 * hi;
                int n  = q0 + ql;
                int d  = dt * 32 + c;
                Ob[((size_t)(b * SEQ + n)) * DIM + hh * DHEAD + d] =
                    f2bf(o[dt][r] * linv[r]);
            }
    }
}

// ---------------------------------------------------------------------------
// Output projection: 64x128 tile, 2-buf db, grid (128,4)=512 -> 2/CU.
// ---------------------------------------------------------------------------
__global__ __launch_bounds__(256, 3) void out_gemm(
        const u16* __restrict__ A, const u16* __restrict__ Wt,
        const void* __restrict__ bias, void* __restrict__ out,
        const int* __restrict__ flag) {
    __shared__ __align__(16) u16 As[2 * 64 * 32];
    __shared__ __align__(16) u16 Bs[2 * 128 * 32];

    int tid  = threadIdx.x;
    int lane = tid & 63, ln = lane & 15, quad = lane >> 4, wid = tid >> 6;
    int m0 = blockIdx.x * 64, n0 = blockIdx.y * 128;
    int wm = (wid >> 1) * 32, wn = (wid & 1) * 64;
    int isbf = *flag;

    f32x4 acc[2][4];
#pragma unroll
    for (int i = 0; i < 2; ++i)
#pragma unroll
        for (int j = 0; j < 4; ++j) acc[i][j] = 0.f;

    gemm_lds_db<DIM, 64, 128>(A, Wt, m0, n0, tid, As, Bs, acc);

#pragma unroll
    for (int j = 0; j < 4; ++j) {
        int col = n0 + wn + j * 16 + ln;        // [0,512)
        float bv = isbf ? bf2f(((const u16*)bias)[col])
                        : ((const float*)bias)[col];
#pragma unroll
        for (int i = 0; i < 2; ++i) {
            int rbase = m0 + wm + i * 16 + quad * 4;
#pragma unroll
            for (int r = 0; r < 4; ++r) {
                int row = rbase + r;
                size_t off = (size_t)row * DIM + col;
                float val = acc[i][j][r] + bv;
                if (isbf) ((u16*)out)[off] = f2bf(val);
                else      ((float*)out)[off] = val;
            }
        }
    }
}

// ---------------------------------------------------------------------------
// kernel_launch — 4 launches: prep (256 blocks), qkv_gemm (fused x ingest),
// flash_attn, out_gemm
// ---------------------------------------------------------------------------
extern "C" void kernel_launch(void* const* d_in, const int* in_sizes, int n_in,
                              void* d_out, int out_size, void* d_ws, size_t ws_size,
                              hipStream_t stream) {
    const void* x     = d_in[0];
    const void* w_qkv = d_in[1];
    const void* w_out = d_in[2];
    const void* b_out = d_in[3];

    int* flag   = (int*)d_ws;
    u16* attn   = (u16*)((char*)d_ws + 16);                 // 8192*512 bf16
    u16* wt_qkv = attn + (size_t)MROWS * DIM;               // 1536*512
    u16* wt_out = wt_qkv + (size_t)NQKV * DIM;              // 512*512
    u16* Qt     = wt_out + (size_t)DIM * DIM;               // 32*64*2048 [bh][d][n]
    u16* Kb     = Qt + (size_t)BH * SEQ * DHEAD;            // [bh][n][d]
    u16* Vt     = Kb + (size_t)BH * SEQ * DHEAD;            // [bh][d][n]

    prep<<<WQT + WOT, 256, 0, stream>>>(
        x, w_qkv, w_out, wt_qkv, wt_out, flag);
    qkv_gemm<<<dim3(MROWS / 128, NQKV / 128), 256, 0, stream>>>(
        x, wt_qkv, Qt, Kb, Vt, flag);
    flash_attn<<<dim3(BH, SEQ / 128), 512, 0, stream>>>(Qt, Kb, Vt, attn);
    out_gemm<<<dim3(MROWS / 64, DIM / 128), 256, 0, stream>>>(
        attn, wt_out, b_out, d_out, flag);
}